// Round 3
// baseline (666.135 us; speedup 1.0000x reference)
//
#include <hip/hip_runtime.h>

// CosineSelfAttention  B=4, S=8192, HID=768, NH=12, HD=64, EPS=1e-5
// Inputs fp32 (runtime-sniffed, bf16 fallback). Compute: bf16 MFMA + fp32 accum.
// OUTPUT fp32 (reference returns fp32). K,V staged as bf16 inside d_out
// (consumed by kv_k before out_k overwrites d_out with fp32 output).

typedef unsigned short u16;
typedef unsigned int u32;

#define B_ 4
#define S_ 8192
#define HID_ 768
#define NH_ 12
#define HD_ 64
#define EPS_ 1e-5f

typedef __attribute__((ext_vector_type(8))) short bf16x8;
typedef __attribute__((ext_vector_type(4))) float f32x4;

__device__ __forceinline__ float bf2f(unsigned int u) {
    u <<= 16;
    return __builtin_bit_cast(float, u);
}
__device__ __forceinline__ u16 f2bf(float f) {
    u32 u = __builtin_bit_cast(u32, f);
    u = u + 0x7fffu + ((u >> 16) & 1u);   // round-to-nearest-even
    return (u16)(u >> 16);
}

// ---------------------------------------------------------------------------
// Kernel 0: dtype sniff. If X is fp32, even u16s are mantissa-low halves:
// (u>>7)&0xFF >= 0xF8 happens w/ p=1/32 per sample -> certain over 8192.
// If X is bf16 N(0,1), that field is the exponent, always < 0x90.
// ---------------------------------------------------------------------------
__global__ void sniff_k(const void* __restrict__ X, u32* __restrict__ flag)
{
    __shared__ int bad;
    if (threadIdx.x == 0) bad = 0;
    __syncthreads();
    const u16* p = (const u16*)X;
    int loc = 0;
    for (int i = threadIdx.x; i < 8192; i += 256) {
        const u32 u = p[2 * i];
        const u32 e = (u >> 7) & 0xFFu;
        if (e >= 0xF8u) loc = 1;
    }
    if (loc) bad = 1;   // benign race
    __syncthreads();
    if (threadIdx.x == 0) *flag = (u32)bad;   // 1 = fp32, 0 = bf16
}

// ---------------------------------------------------------------------------
// Kernel 1: fused QKV GEMM (+bias, +mask, +cosine norm for Q/K)
// C[m,n] = sum_k X[m,k]*W[n,k]; 128x128 tile, BK=64, 4 waves (2x2 of 64x64)
// ---------------------------------------------------------------------------
__global__ __launch_bounds__(256) void gemm_qkv_k(
    const void* __restrict__ X,
    const void* __restrict__ Wq, const void* __restrict__ Wk, const void* __restrict__ Wv,
    const void* __restrict__ bq, const void* __restrict__ bk, const void* __restrict__ bvs,
    const void* __restrict__ mask,
    const u32* __restrict__ flagp,
    u16* __restrict__ Qb, u16* __restrict__ Kb, u16* __restrict__ Vb)
{
    constexpr int BK = 64;
    __shared__ u16 smem[128 * 136];        // staging (2x 128x64) then repack (128x136)
    u16* lA = smem;
    u16* lB = smem + 128 * 64;

    const int tid  = threadIdx.x;
    const int lane = tid & 63;
    const int wid  = tid >> 6;
    const int wm   = wid >> 1, wn = wid & 1;
    const int flagv = (int)*flagp;

    const int bid   = blockIdx.x;
    const int row_t = bid / 18;
    const int nc    = bid % 18;
    const int mat   = nc / 6;
    const int ncol  = nc % 6;
    const void* W    = (mat == 0) ? Wq : (mat == 1) ? Wk : Wv;
    const void* bias = (mat == 0) ? bq : (mat == 1) ? bk : bvs;
    u16* outb        = (mat == 0) ? Qb : (mat == 1) ? Kb : Vb;

    const int arow0 = row_t * 128;
    const int brow0 = ncol * 128;

    f32x4 acc[4][4];
#pragma unroll
    for (int i = 0; i < 4; ++i)
#pragma unroll
        for (int j = 0; j < 4; ++j) acc[i][j] = (f32x4){0.f, 0.f, 0.f, 0.f};

    for (int k0 = 0; k0 < HID_; k0 += BK) {
        if (!flagv) {
            const u16* Xp = (const u16*)X;
            const u16* Wp = (const u16*)W;
#pragma unroll
            for (int c = 0; c < 4; ++c) {
                const int lin = c * 2048 + tid * 8;
                const int row = lin >> 6, col = lin & 63;
                *(uint4*)(lA + lin) = *(const uint4*)(Xp + (size_t)(arow0 + row) * HID_ + k0 + col);
                *(uint4*)(lB + lin) = *(const uint4*)(Wp + (size_t)(brow0 + row) * HID_ + k0 + col);
            }
        } else {
            const float* Xf = (const float*)X;
            const float* Wf = (const float*)W;
#pragma unroll
            for (int c = 0; c < 4; ++c) {
                const int lin = c * 2048 + tid * 8;
                const int row = lin >> 6, col = lin & 63;
                {
                    const float* g = Xf + (size_t)(arow0 + row) * HID_ + k0 + col;
                    const float4 lo = *(const float4*)(g);
                    const float4 hi = *(const float4*)(g + 4);
                    uint4 o;
                    o.x = (u32)f2bf(lo.x) | ((u32)f2bf(lo.y) << 16);
                    o.y = (u32)f2bf(lo.z) | ((u32)f2bf(lo.w) << 16);
                    o.z = (u32)f2bf(hi.x) | ((u32)f2bf(hi.y) << 16);
                    o.w = (u32)f2bf(hi.z) | ((u32)f2bf(hi.w) << 16);
                    *(uint4*)(lA + lin) = o;
                }
                {
                    const float* g = Wf + (size_t)(brow0 + row) * HID_ + k0 + col;
                    const float4 lo = *(const float4*)(g);
                    const float4 hi = *(const float4*)(g + 4);
                    uint4 o;
                    o.x = (u32)f2bf(lo.x) | ((u32)f2bf(lo.y) << 16);
                    o.y = (u32)f2bf(lo.z) | ((u32)f2bf(lo.w) << 16);
                    o.z = (u32)f2bf(hi.x) | ((u32)f2bf(hi.y) << 16);
                    o.w = (u32)f2bf(hi.z) | ((u32)f2bf(hi.w) << 16);
                    *(uint4*)(lB + lin) = o;
                }
            }
        }
        __syncthreads();
#pragma unroll
        for (int ks = 0; ks < 2; ++ks) {
            bf16x8 af[4], bfr[4];
#pragma unroll
            for (int i = 0; i < 4; ++i)
                af[i] = *(const bf16x8*)(lA + (wm * 64 + i * 16 + (lane & 15)) * BK + ks * 32 + (lane >> 4) * 8);
#pragma unroll
            for (int j = 0; j < 4; ++j)
                bfr[j] = *(const bf16x8*)(lB + (wn * 64 + j * 16 + (lane & 15)) * BK + ks * 32 + (lane >> 4) * 8);
#pragma unroll
            for (int i = 0; i < 4; ++i)
#pragma unroll
                for (int j = 0; j < 4; ++j)
                    acc[i][j] = __builtin_amdgcn_mfma_f32_16x16x32_bf16(af[i], bfr[j], acc[i][j], 0, 0, 0);
        }
        __syncthreads();
    }

    // ---- epilogue: bias, then (Q/K only) mask + cosine normalize per token-row
    float bias4[4];
#pragma unroll
    for (int j = 0; j < 4; ++j) {
        const int idx = brow0 + wn * 64 + j * 16 + (lane & 15);
        bias4[j] = flagv ? ((const float*)bias)[idx] : bf2f(((const u16*)bias)[idx]);
    }
#pragma unroll
    for (int i = 0; i < 4; ++i)
#pragma unroll
        for (int j = 0; j < 4; ++j)
#pragma unroll
            for (int r = 0; r < 4; ++r) acc[i][j][r] += bias4[j];

    float scale[4][4];
    if (mat < 2) {
        // wave's 64 cols = exactly one head
#pragma unroll
        for (int i = 0; i < 4; ++i) {
#pragma unroll
            for (int r = 0; r < 4; ++r) {
                float ss = 0.f;
#pragma unroll
                for (int j = 0; j < 4; ++j) ss += acc[i][j][r] * acc[i][j][r];
#pragma unroll
                for (int off = 1; off < 16; off <<= 1) ss += __shfl_xor(ss, off, 64);
                const int grow = arow0 + wm * 64 + i * 16 + (lane >> 4) * 4 + r;
                const int bb = grow >> 13, s = grow & (S_ - 1);
                const float mk = flagv ? ((const float*)mask)[bb * S_ + s]
                                       : bf2f(((const u16*)mask)[bb * S_ + s]);
                const float mf = (mk == 0.f) ? 1.f : 0.f;     // m = 1 - binarize(mask)
                scale[i][r] = mf / (sqrtf(ss) + EPS_);
            }
        }
    } else {
#pragma unroll
        for (int i = 0; i < 4; ++i)
#pragma unroll
            for (int r = 0; r < 4; ++r) scale[i][r] = 1.f;
    }

    // repack via LDS (stride 136: 16B-aligned rows, staggered banks)
#pragma unroll
    for (int i = 0; i < 4; ++i)
#pragma unroll
        for (int j = 0; j < 4; ++j)
#pragma unroll
            for (int r = 0; r < 4; ++r) {
                const int rr = wm * 64 + i * 16 + (lane >> 4) * 4 + r;
                const int cc = wn * 64 + j * 16 + (lane & 15);
                smem[rr * 136 + cc] = f2bf(acc[i][j][r] * scale[i][r]);
            }
    __syncthreads();
#pragma unroll
    for (int it = 0; it < 8; ++it) {
        const int lin = it * 2048 + tid * 8;
        const int r = lin >> 7;
        const int c = lin & 127;
        const uint4 v = *(const uint4*)(smem + r * 136 + c);
        *(uint4*)(outb + (size_t)(arow0 + r) * HID_ + brow0 + c) = v;
    }
}

// ---------------------------------------------------------------------------
// Kernel 2: msum[b] = count of mask[b,s]==0
// ---------------------------------------------------------------------------
__global__ __launch_bounds__(256) void msum_k(const void* __restrict__ mask,
                                              const u32* __restrict__ flagp,
                                              float* __restrict__ msumws)
{
    const int b = blockIdx.x, tid = threadIdx.x;
    const int flagv = (int)*flagp;
    float loc = 0.f;
    for (int i = 0; i < 32; ++i) {
        const int idx = b * S_ + i * 256 + tid;
        const float mv = flagv ? ((const float*)mask)[idx] : bf2f(((const u16*)mask)[idx]);
        loc += (mv == 0.f) ? 1.f : 0.f;
    }
#pragma unroll
    for (int off = 32; off > 0; off >>= 1) loc += __shfl_down(loc, off, 64);
    __shared__ float red[4];
    if ((tid & 63) == 0) red[tid >> 6] = loc;
    __syncthreads();
    if (tid == 0) msumws[b] = red[0] + red[1] + red[2] + red[3];
}

// ---------------------------------------------------------------------------
// Kernel 3: kv[bh,d,e] += sum_s kn*v ; ksum, vsum partials (fp32 atomics)
// grid (48, 16): (b,h) x S-chunk of 512
// ---------------------------------------------------------------------------
__global__ __launch_bounds__(256) void kv_k(
    const u16* __restrict__ Kb, const u16* __restrict__ Vb,
    float* __restrict__ kvws, float* __restrict__ ksumws, float* __restrict__ vsumws)
{
    __shared__ u16 lK[64 * 64];
    __shared__ u16 lV[64 * 64];
    const int tid = threadIdx.x;
    const int bh = blockIdx.x;
    const int b = bh / NH_, h = bh % NH_;
    const int tx = tid & 15, ty = tid >> 4;

    float acc[4][4] = {};
    float ksp[4] = {0.f, 0.f, 0.f, 0.f}, vsp[4] = {0.f, 0.f, 0.f, 0.f};

    const int s_base = blockIdx.y * 512;
    for (int t = 0; t < 8; ++t) {
        const int s0 = s_base + t * 64;
#pragma unroll
        for (int it = 0; it < 2; ++it) {
            const int cidx = it * 256 + tid;      // 512 chunks of 8 elems
            const int row = cidx >> 3, seg = cidx & 7;
            const size_t goff = (size_t)(b * S_ + s0 + row) * HID_ + h * HD_ + seg * 8;
            *(uint4*)(lK + row * 64 + seg * 8) = *(const uint4*)(Kb + goff);
            *(uint4*)(lV + row * 64 + seg * 8) = *(const uint4*)(Vb + goff);
        }
        __syncthreads();
#pragma unroll 4
        for (int s = 0; s < 64; ++s) {
            const uint2 ku = *(const uint2*)(lK + s * 64 + tx * 4);
            const uint2 vu = *(const uint2*)(lV + s * 64 + ty * 4);
            float k4[4], v4[4];
            k4[0] = bf2f(ku.x & 0xffffu); k4[1] = bf2f(ku.x >> 16);
            k4[2] = bf2f(ku.y & 0xffffu); k4[3] = bf2f(ku.y >> 16);
            v4[0] = bf2f(vu.x & 0xffffu); v4[1] = bf2f(vu.x >> 16);
            v4[2] = bf2f(vu.y & 0xffffu); v4[3] = bf2f(vu.y >> 16);
#pragma unroll
            for (int i = 0; i < 4; ++i)
#pragma unroll
                for (int j = 0; j < 4; ++j) acc[i][j] += k4[i] * v4[j];
            if (ty == 0) {
#pragma unroll
                for (int i = 0; i < 4; ++i) ksp[i] += k4[i];
            }
            if (tx == 0) {
#pragma unroll
                for (int j = 0; j < 4; ++j) vsp[j] += v4[j];
            }
        }
        __syncthreads();
    }
#pragma unroll
    for (int i = 0; i < 4; ++i)
#pragma unroll
        for (int j = 0; j < 4; ++j)
            atomicAdd(&kvws[bh * 4096 + (tx * 4 + i) * 64 + ty * 4 + j], acc[i][j]);
    if (ty == 0) {
#pragma unroll
        for (int i = 0; i < 4; ++i) atomicAdd(&ksumws[bh * 64 + tx * 4 + i], ksp[i]);
    }
    if (tx == 0) {
#pragma unroll
        for (int j = 0; j < 4; ++j) atomicAdd(&vsumws[bh * 64 + ty * 4 + j], vsp[j]);
    }
}

// ---------------------------------------------------------------------------
// Kernel 4: out[b,s,h,:] = (q@kv + vsum) / (q.ksum + eps + msum[b]) -> fp32
// Q read from ws (bf16); output written fp32 to d_out (overwrites K/V staging,
// which kv_k has already consumed).
// grid (48, 32): (b,h) x s-tile of 256; one token per thread
// ---------------------------------------------------------------------------
__global__ __launch_bounds__(256) void out_k(
    const u16* __restrict__ Qb,
    const float* __restrict__ kvws, const float* __restrict__ ksumws,
    const float* __restrict__ vsumws, const float* __restrict__ msumws,
    float* __restrict__ out)
{
    __shared__ float lkv[4096];
    __shared__ float lks[64];
    __shared__ float lvs[64];
    const int tid = threadIdx.x;
    const int bh = blockIdx.x;
    const int b = bh / NH_, h = bh % NH_;
#pragma unroll
    for (int it = 0; it < 16; ++it)
        lkv[it * 256 + tid] = kvws[bh * 4096 + it * 256 + tid];
    if (tid < 64) {
        lks[tid] = ksumws[bh * 64 + tid];
        lvs[tid] = vsumws[bh * 64 + tid];
    }
    __syncthreads();

    const int s = blockIdx.y * 256 + tid;
    const float msum = msumws[b];
    float q[64];
    const u16* qp = Qb + (size_t)(b * S_ + s) * HID_ + h * HD_;
#pragma unroll
    for (int c = 0; c < 8; ++c) {
        const uint4 u = *(const uint4*)(qp + c * 8);
        q[c * 8 + 0] = bf2f(u.x & 0xffffu); q[c * 8 + 1] = bf2f(u.x >> 16);
        q[c * 8 + 2] = bf2f(u.y & 0xffffu); q[c * 8 + 3] = bf2f(u.y >> 16);
        q[c * 8 + 4] = bf2f(u.z & 0xffffu); q[c * 8 + 5] = bf2f(u.z >> 16);
        q[c * 8 + 6] = bf2f(u.w & 0xffffu); q[c * 8 + 7] = bf2f(u.w >> 16);
    }
    float den = EPS_ + msum;
#pragma unroll
    for (int d = 0; d < 64; ++d) den += q[d] * lks[d];
    const float inv = 1.f / den;

    float* op = out + (size_t)(b * S_ + s) * HID_ + h * HD_;
    for (int eg = 0; eg < 16; ++eg) {
        float a0 = lvs[eg * 4 + 0], a1 = lvs[eg * 4 + 1];
        float a2 = lvs[eg * 4 + 2], a3 = lvs[eg * 4 + 3];
#pragma unroll
        for (int d = 0; d < 64; ++d) {
            const float4 kvv = *(const float4*)(lkv + d * 64 + eg * 4);
            const float qd = q[d];
            a0 += qd * kvv.x; a1 += qd * kvv.y; a2 += qd * kvv.z; a3 += qd * kvv.w;
        }
        float4 o;
        o.x = a0 * inv; o.y = a1 * inv; o.z = a2 * inv; o.w = a3 * inv;
        *(float4*)(op + eg * 4) = o;
    }
}

// ---------------------------------------------------------------------------
extern "C" void kernel_launch(void* const* d_in, const int* in_sizes, int n_in,
                              void* d_out, int out_size, void* d_ws, size_t ws_size,
                              hipStream_t stream) {
    const void* X   = d_in[0];
    const void* msk = d_in[1];
    const void* Wq  = d_in[2];
    const void* bq  = d_in[3];
    const void* Wk  = d_in[4];
    const void* bk  = d_in[5];
    const void* Wv  = d_in[6];
    const void* bv  = d_in[7];

    char* ws = (char*)d_ws;
    float* kvws   = (float*)ws;                 // 48*4096 fp32
    float* ksumws = kvws + 48 * 4096;           // 48*64
    float* vsumws = ksumws + 48 * 64;           // 48*64
    float* msumws = vsumws + 48 * 64;           // 4
    u32*   flagp  = (u32*)(msumws + 4);
    u16* Qb = (u16*)(ws + (1 << 20));           // 48 MB bf16 Q in ws
    u16* Kb = (u16*)d_out;                      // 48 MB bf16 K staged in d_out
    u16* Vb = Kb + (size_t)32768 * 768;         // 48 MB bf16 V staged in d_out

    hipMemsetAsync(d_ws, 0, (size_t)(48 * 4096 + 48 * 64 * 2 + 8) * sizeof(float), stream);

    hipLaunchKernelGGL(sniff_k, dim3(1), dim3(256), 0, stream, X, flagp);
    hipLaunchKernelGGL(gemm_qkv_k, dim3(4608), dim3(256), 0, stream,
                       X, Wq, Wk, Wv, bq, bk, bv, msk, flagp, Qb, Kb, Vb);
    hipLaunchKernelGGL(msum_k, dim3(4), dim3(256), 0, stream, msk, flagp, msumws);
    hipLaunchKernelGGL(kv_k, dim3(48, 16), dim3(256), 0, stream,
                       Kb, Vb, kvws, ksumws, vsumws);
    hipLaunchKernelGGL(out_k, dim3(48, 32), dim3(256), 0, stream,
                       Qb, kvws, ksumws, vsumws, msumws, (float*)d_out);
}

// Round 4
// 584.129 us; speedup vs baseline: 1.1404x; 1.1404x over previous
//
#include <hip/hip_runtime.h>

// CosineSelfAttention  B=4, S=8192, HID=768, NH=12, HD=64, EPS=1e-5
// Inputs fp32 (runtime-sniffed, bf16 fallback). Compute: bf16 MFMA + fp32 accum.
// OUTPUT fp32. K,V staged bf16 inside d_out (consumed by kv_k before out_k
// overwrites d_out). W pre-converted to bf16 in ws; X converted on the fly.
// LDS layout uses seg-XOR swizzle: LDS[row][seg] = global[row][seg ^ (row&7)]
// so frag ds_read_b128 hits the 32-bank floor (was 16-lanes-on-4-banks).

typedef unsigned short u16;
typedef unsigned int u32;

#define B_ 4
#define S_ 8192
#define HID_ 768
#define NH_ 12
#define HD_ 64
#define EPS_ 1e-5f

typedef __attribute__((ext_vector_type(8))) short bf16x8;
typedef __attribute__((ext_vector_type(4))) float f32x4;

__device__ __forceinline__ float bf2f(unsigned int u) {
    u <<= 16;
    return __builtin_bit_cast(float, u);
}
__device__ __forceinline__ u16 f2bf(float f) {
    u32 u = __builtin_bit_cast(u32, f);
    u = u + 0x7fffu + ((u >> 16) & 1u);   // round-to-nearest-even
    return (u16)(u >> 16);
}

// async global->LDS, 16B per lane; LDS dest = wave-uniform base + lane*16
#define ASYNC16(gptr, lptr)                                                        \
    __builtin_amdgcn_global_load_lds(                                              \
        (const __attribute__((address_space(1))) void*)(gptr),                     \
        (__attribute__((address_space(3))) void*)(lptr), 16, 0, 0)

// ---------------------------------------------------------------------------
// Kernel 0: dtype sniff (1 = fp32, 0 = bf16)
// ---------------------------------------------------------------------------
__global__ void sniff_k(const void* __restrict__ X, u32* __restrict__ flag)
{
    __shared__ int bad;
    if (threadIdx.x == 0) bad = 0;
    __syncthreads();
    const u16* p = (const u16*)X;
    int loc = 0;
    for (int i = threadIdx.x; i < 8192; i += 256) {
        const u32 u = p[2 * i];
        const u32 e = (u >> 7) & 0xFFu;
        if (e >= 0xF8u) loc = 1;
    }
    if (loc) bad = 1;   // benign race
    __syncthreads();
    if (threadIdx.x == 0) *flag = (u32)bad;
}

// ---------------------------------------------------------------------------
// Kernel 0b: convert Wq|Wk|Wv (fp32 or bf16) -> bf16 contiguous in ws.
// grid 864 blocks of 256; 288 blocks per matrix; 8 elems/thread.
// ---------------------------------------------------------------------------
__global__ __launch_bounds__(256) void wconv_k(
    const void* __restrict__ Wq, const void* __restrict__ Wk, const void* __restrict__ Wv,
    const u32* __restrict__ flagp, u16* __restrict__ Wb)
{
    const int mat = blockIdx.x / 288;
    const int blk = blockIdx.x % 288;
    const void* src = (mat == 0) ? Wq : (mat == 1) ? Wk : Wv;
    u16* dst = Wb + (size_t)mat * 589824;
    const int e = blk * 2048 + threadIdx.x * 8;
    if (*flagp) {
        const float* s = (const float*)src + e;
        const float4 lo = *(const float4*)(s);
        const float4 hi = *(const float4*)(s + 4);
        uint4 o;
        o.x = (u32)f2bf(lo.x) | ((u32)f2bf(lo.y) << 16);
        o.y = (u32)f2bf(lo.z) | ((u32)f2bf(lo.w) << 16);
        o.z = (u32)f2bf(hi.x) | ((u32)f2bf(hi.y) << 16);
        o.w = (u32)f2bf(hi.z) | ((u32)f2bf(hi.w) << 16);
        *(uint4*)(dst + e) = o;
    } else {
        *(uint4*)(dst + e) = *(const uint4*)((const u16*)src + e);
    }
}

// ---------------------------------------------------------------------------
// Kernel 1: fused QKV GEMM (+bias, +mask, +cosine norm for Q/K)
// C[m,n] = sum_k X[m,k]*W[n,k]; 128x128 tile, BK=64, 4 waves (2x2 of 64x64)
// A: fp32->bf16 on-the-fly into swizzled LDS; B: ASYNC16 from bf16 Wb with
// swizzled global source (LDS dest contiguous).
// ---------------------------------------------------------------------------
__global__ __launch_bounds__(256) void gemm_qkv_k(
    const void* __restrict__ X,
    const u16* __restrict__ Wb,
    const void* __restrict__ bq, const void* __restrict__ bk, const void* __restrict__ bvs,
    const void* __restrict__ mask,
    const u32* __restrict__ flagp,
    u16* __restrict__ Qb, u16* __restrict__ Kb, u16* __restrict__ Vb)
{
    __shared__ u16 smem[128 * 136];        // staging (2x 128x64) then repack (128x136)
    u16* lA = smem;
    u16* lB = smem + 128 * 64;

    const int tid  = threadIdx.x;
    const int lane = tid & 63;
    const int wid  = tid >> 6;
    const int wm   = wid >> 1, wn = wid & 1;
    const int flagv = (int)*flagp;

    const int bid   = blockIdx.x;
    const int row_t = bid / 18;
    const int nc    = bid % 18;
    const int mat   = nc / 6;
    const int ncol  = nc % 6;
    const u16* W     = Wb + (size_t)mat * 589824;
    const void* bias = (mat == 0) ? bq : (mat == 1) ? bk : bvs;
    u16* outb        = (mat == 0) ? Qb : (mat == 1) ? Kb : Vb;

    const int arow0 = row_t * 128;
    const int brow0 = ncol * 128;

    // B staging geometry (per wave, 4 calls of 1KB): row = chunk*8 + (lane>>3)
    const int brow_l = lane >> 3;                 // 0..7 within 8-row chunk
    const int bseg_l = lane & 7;                  // physical seg this lane fills

    f32x4 acc[4][4];
#pragma unroll
    for (int i = 0; i < 4; ++i)
#pragma unroll
        for (int j = 0; j < 4; ++j) acc[i][j] = (f32x4){0.f, 0.f, 0.f, 0.f};

    for (int k0 = 0; k0 < HID_; k0 += 64) {
        // ---- B tile via global_load_lds (bf16, swizzled source)
#pragma unroll
        for (int t = 0; t < 4; ++t) {
            const int chunk = wid * 4 + t;        // 16 chunks of 8 rows
            const int row = chunk * 8 + brow_l;
            const int gseg = bseg_l ^ (row & 7);  // LDS[row][bseg_l] = g[row][gseg]
            const u16* gb = W + (size_t)(brow0 + row) * HID_ + k0 + gseg * 8;
            ASYNC16(gb, lB + chunk * 512);        // 512 u16 = 1KB per call
        }
        // ---- A tile: fp32 (or bf16) -> swizzled LDS via ds_write
        if (flagv) {
            const float* Xf = (const float*)X;
#pragma unroll
            for (int c = 0; c < 4; ++c) {
                const int lin = c * 2048 + tid * 8;
                const int row = lin >> 6, col = lin & 63;
                const int phys = ((col >> 3) ^ (row & 7)) * 8;
                const float* g = Xf + (size_t)(arow0 + row) * HID_ + k0 + col;
                const float4 lo = *(const float4*)(g);
                const float4 hi = *(const float4*)(g + 4);
                uint4 o;
                o.x = (u32)f2bf(lo.x) | ((u32)f2bf(lo.y) << 16);
                o.y = (u32)f2bf(lo.z) | ((u32)f2bf(lo.w) << 16);
                o.z = (u32)f2bf(hi.x) | ((u32)f2bf(hi.y) << 16);
                o.w = (u32)f2bf(hi.z) | ((u32)f2bf(hi.w) << 16);
                *(uint4*)(lA + row * 64 + phys) = o;
            }
        } else {
            const u16* Xp = (const u16*)X;
#pragma unroll
            for (int c = 0; c < 4; ++c) {
                const int lin = c * 2048 + tid * 8;
                const int row = lin >> 6, col = lin & 63;
                const int phys = ((col >> 3) ^ (row & 7)) * 8;
                *(uint4*)(lA + row * 64 + phys) =
                    *(const uint4*)(Xp + (size_t)(arow0 + row) * HID_ + k0 + col);
            }
        }
        __syncthreads();                 // drains vmcnt (ASYNC16) + lgkmcnt
#pragma unroll
        for (int ks = 0; ks < 2; ++ks) {
            const int phys = ((ks * 4 + (lane >> 4)) ^ (lane & 7)) * 8;  // row&7==lane&7
            bf16x8 af[4], bfr[4];
#pragma unroll
            for (int i = 0; i < 4; ++i)
                af[i] = *(const bf16x8*)(lA + (wm * 64 + i * 16 + (lane & 15)) * 64 + phys);
#pragma unroll
            for (int j = 0; j < 4; ++j)
                bfr[j] = *(const bf16x8*)(lB + (wn * 64 + j * 16 + (lane & 15)) * 64 + phys);
#pragma unroll
            for (int i = 0; i < 4; ++i)
#pragma unroll
                for (int j = 0; j < 4; ++j)
                    acc[i][j] = __builtin_amdgcn_mfma_f32_16x16x32_bf16(af[i], bfr[j], acc[i][j], 0, 0, 0);
        }
        __syncthreads();
    }

    // ---- epilogue: bias, then (Q/K only) mask + cosine normalize per token-row
    float bias4[4];
#pragma unroll
    for (int j = 0; j < 4; ++j) {
        const int idx = brow0 + wn * 64 + j * 16 + (lane & 15);
        bias4[j] = flagv ? ((const float*)bias)[idx] : bf2f(((const u16*)bias)[idx]);
    }
#pragma unroll
    for (int i = 0; i < 4; ++i)
#pragma unroll
        for (int j = 0; j < 4; ++j)
#pragma unroll
            for (int r = 0; r < 4; ++r) acc[i][j][r] += bias4[j];

    float scale[4][4];
    if (mat < 2) {
        // wave's 64 cols = exactly one head
#pragma unroll
        for (int i = 0; i < 4; ++i) {
#pragma unroll
            for (int r = 0; r < 4; ++r) {
                float ss = 0.f;
#pragma unroll
                for (int j = 0; j < 4; ++j) ss += acc[i][j][r] * acc[i][j][r];
#pragma unroll
                for (int off = 1; off < 16; off <<= 1) ss += __shfl_xor(ss, off, 64);
                const int grow = arow0 + wm * 64 + i * 16 + (lane >> 4) * 4 + r;
                const int bb = grow >> 13, s = grow & (S_ - 1);
                const float mk = flagv ? ((const float*)mask)[bb * S_ + s]
                                       : bf2f(((const u16*)mask)[bb * S_ + s]);
                const float mf = (mk == 0.f) ? 1.f : 0.f;     // m = 1 - binarize(mask)
                scale[i][r] = mf / (sqrtf(ss) + EPS_);
            }
        }
    } else {
#pragma unroll
        for (int i = 0; i < 4; ++i)
#pragma unroll
            for (int r = 0; r < 4; ++r) scale[i][r] = 1.f;
    }

    // repack via LDS (stride 136: 16B-aligned rows, staggered banks)
#pragma unroll
    for (int i = 0; i < 4; ++i)
#pragma unroll
        for (int j = 0; j < 4; ++j)
#pragma unroll
            for (int r = 0; r < 4; ++r) {
                const int rr = wm * 64 + i * 16 + (lane >> 4) * 4 + r;
                const int cc = wn * 64 + j * 16 + (lane & 15);
                smem[rr * 136 + cc] = f2bf(acc[i][j][r] * scale[i][r]);
            }
    __syncthreads();
#pragma unroll
    for (int it = 0; it < 8; ++it) {
        const int lin = it * 2048 + tid * 8;
        const int r = lin >> 7;
        const int c = lin & 127;
        const uint4 v = *(const uint4*)(smem + r * 136 + c);
        *(uint4*)(outb + (size_t)(arow0 + r) * HID_ + brow0 + c) = v;
    }
}

// ---------------------------------------------------------------------------
// Kernel 2: msum[b] = count of mask[b,s]==0
// ---------------------------------------------------------------------------
__global__ __launch_bounds__(256) void msum_k(const void* __restrict__ mask,
                                              const u32* __restrict__ flagp,
                                              float* __restrict__ msumws)
{
    const int b = blockIdx.x, tid = threadIdx.x;
    const int flagv = (int)*flagp;
    float loc = 0.f;
    for (int i = 0; i < 32; ++i) {
        const int idx = b * S_ + i * 256 + tid;
        const float mv = flagv ? ((const float*)mask)[idx] : bf2f(((const u16*)mask)[idx]);
        loc += (mv == 0.f) ? 1.f : 0.f;
    }
#pragma unroll
    for (int off = 32; off > 0; off >>= 1) loc += __shfl_down(loc, off, 64);
    __shared__ float red[4];
    if ((tid & 63) == 0) red[tid >> 6] = loc;
    __syncthreads();
    if (tid == 0) msumws[b] = red[0] + red[1] + red[2] + red[3];
}

// ---------------------------------------------------------------------------
// Kernel 3: kv[bh,d,e] += sum_s kn*v ; ksum, vsum partials (fp32 atomics)
// grid (48, 16): (b,h) x S-chunk of 512
// ---------------------------------------------------------------------------
__global__ __launch_bounds__(256) void kv_k(
    const u16* __restrict__ Kb, const u16* __restrict__ Vb,
    float* __restrict__ kvws, float* __restrict__ ksumws, float* __restrict__ vsumws)
{
    __shared__ u16 lK[64 * 64];
    __shared__ u16 lV[64 * 64];
    const int tid = threadIdx.x;
    const int bh = blockIdx.x;
    const int b = bh / NH_, h = bh % NH_;
    const int tx = tid & 15, ty = tid >> 4;

    float acc[4][4] = {};
    float ksp[4] = {0.f, 0.f, 0.f, 0.f}, vsp[4] = {0.f, 0.f, 0.f, 0.f};

    const int s_base = blockIdx.y * 512;
    for (int t = 0; t < 8; ++t) {
        const int s0 = s_base + t * 64;
#pragma unroll
        for (int it = 0; it < 2; ++it) {
            const int cidx = it * 256 + tid;
            const int row = cidx >> 3, seg = cidx & 7;
            const size_t goff = (size_t)(b * S_ + s0 + row) * HID_ + h * HD_ + seg * 8;
            *(uint4*)(lK + row * 64 + seg * 8) = *(const uint4*)(Kb + goff);
            *(uint4*)(lV + row * 64 + seg * 8) = *(const uint4*)(Vb + goff);
        }
        __syncthreads();
#pragma unroll 4
        for (int s = 0; s < 64; ++s) {
            const uint2 ku = *(const uint2*)(lK + s * 64 + tx * 4);
            const uint2 vu = *(const uint2*)(lV + s * 64 + ty * 4);
            float k4[4], v4[4];
            k4[0] = bf2f(ku.x & 0xffffu); k4[1] = bf2f(ku.x >> 16);
            k4[2] = bf2f(ku.y & 0xffffu); k4[3] = bf2f(ku.y >> 16);
            v4[0] = bf2f(vu.x & 0xffffu); v4[1] = bf2f(vu.x >> 16);
            v4[2] = bf2f(vu.y & 0xffffu); v4[3] = bf2f(vu.y >> 16);
#pragma unroll
            for (int i = 0; i < 4; ++i)
#pragma unroll
                for (int j = 0; j < 4; ++j) acc[i][j] += k4[i] * v4[j];
            if (ty == 0) {
#pragma unroll
                for (int i = 0; i < 4; ++i) ksp[i] += k4[i];
            }
            if (tx == 0) {
#pragma unroll
                for (int j = 0; j < 4; ++j) vsp[j] += v4[j];
            }
        }
        __syncthreads();
    }
#pragma unroll
    for (int i = 0; i < 4; ++i)
#pragma unroll
        for (int j = 0; j < 4; ++j)
            atomicAdd(&kvws[bh * 4096 + (tx * 4 + i) * 64 + ty * 4 + j], acc[i][j]);
    if (ty == 0) {
#pragma unroll
        for (int i = 0; i < 4; ++i) atomicAdd(&ksumws[bh * 64 + tx * 4 + i], ksp[i]);
    }
    if (tx == 0) {
#pragma unroll
        for (int j = 0; j < 4; ++j) atomicAdd(&vsumws[bh * 64 + ty * 4 + j], vsp[j]);
    }
}

// ---------------------------------------------------------------------------
// Kernel 4: out[b,s,h,:] = (q@kv + vsum) / (q.ksum + eps + msum[b]) -> fp32
// ---------------------------------------------------------------------------
__global__ __launch_bounds__(256) void out_k(
    const u16* __restrict__ Qb,
    const float* __restrict__ kvws, const float* __restrict__ ksumws,
    const float* __restrict__ vsumws, const float* __restrict__ msumws,
    float* __restrict__ out)
{
    __shared__ float lkv[4096];
    __shared__ float lks[64];
    __shared__ float lvs[64];
    const int tid = threadIdx.x;
    const int bh = blockIdx.x;
    const int b = bh / NH_, h = bh % NH_;
#pragma unroll
    for (int it = 0; it < 16; ++it)
        lkv[it * 256 + tid] = kvws[bh * 4096 + it * 256 + tid];
    if (tid < 64) {
        lks[tid] = ksumws[bh * 64 + tid];
        lvs[tid] = vsumws[bh * 64 + tid];
    }
    __syncthreads();

    const int s = blockIdx.y * 256 + tid;
    const float msum = msumws[b];
    float q[64];
    const u16* qp = Qb + (size_t)(b * S_ + s) * HID_ + h * HD_;
#pragma unroll
    for (int c = 0; c < 8; ++c) {
        const uint4 u = *(const uint4*)(qp + c * 8);
        q[c * 8 + 0] = bf2f(u.x & 0xffffu); q[c * 8 + 1] = bf2f(u.x >> 16);
        q[c * 8 + 2] = bf2f(u.y & 0xffffu); q[c * 8 + 3] = bf2f(u.y >> 16);
        q[c * 8 + 4] = bf2f(u.z & 0xffffu); q[c * 8 + 5] = bf2f(u.z >> 16);
        q[c * 8 + 6] = bf2f(u.w & 0xffffu); q[c * 8 + 7] = bf2f(u.w >> 16);
    }
    float den = EPS_ + msum;
#pragma unroll
    for (int d = 0; d < 64; ++d) den += q[d] * lks[d];
    const float inv = 1.f / den;

    float* op = out + (size_t)(b * S_ + s) * HID_ + h * HD_;
    for (int eg = 0; eg < 16; ++eg) {
        float a0 = lvs[eg * 4 + 0], a1 = lvs[eg * 4 + 1];
        float a2 = lvs[eg * 4 + 2], a3 = lvs[eg * 4 + 3];
#pragma unroll
        for (int d = 0; d < 64; ++d) {
            const float4 kvv = *(const float4*)(lkv + d * 64 + eg * 4);
            const float qd = q[d];
            a0 += qd * kvv.x; a1 += qd * kvv.y; a2 += qd * kvv.z; a3 += qd * kvv.w;
        }
        float4 o;
        o.x = a0 * inv; o.y = a1 * inv; o.z = a2 * inv; o.w = a3 * inv;
        *(float4*)(op + eg * 4) = o;
    }
}

// ---------------------------------------------------------------------------
extern "C" void kernel_launch(void* const* d_in, const int* in_sizes, int n_in,
                              void* d_out, int out_size, void* d_ws, size_t ws_size,
                              hipStream_t stream) {
    const void* X   = d_in[0];
    const void* msk = d_in[1];
    const void* Wq  = d_in[2];
    const void* bq  = d_in[3];
    const void* Wk  = d_in[4];
    const void* bk  = d_in[5];
    const void* Wv  = d_in[6];
    const void* bv  = d_in[7];

    char* ws = (char*)d_ws;
    float* kvws   = (float*)ws;                 // 48*4096 fp32
    float* ksumws = kvws + 48 * 4096;           // 48*64
    float* vsumws = ksumws + 48 * 64;           // 48*64
    float* msumws = vsumws + 48 * 64;           // 4
    u32*   flagp  = (u32*)(msumws + 4);
    u16* Wb = (u16*)(ws + (1 << 20));           // 3 * 1.125 MB bf16 weights
    u16* Qb = (u16*)(ws + 5 * (1 << 20));       // 48 MB bf16 Q
    u16* Kb = (u16*)d_out;                      // 48 MB bf16 K staged in d_out
    u16* Vb = Kb + (size_t)32768 * 768;         // 48 MB bf16 V staged in d_out

    hipMemsetAsync(d_ws, 0, (size_t)(48 * 4096 + 48 * 64 * 2 + 8) * sizeof(float), stream);

    hipLaunchKernelGGL(sniff_k, dim3(1), dim3(256), 0, stream, X, flagp);
    hipLaunchKernelGGL(wconv_k, dim3(864), dim3(256), 0, stream, Wq, Wk, Wv, flagp, Wb);
    hipLaunchKernelGGL(gemm_qkv_k, dim3(4608), dim3(256), 0, stream,
                       X, Wb, bq, bk, bv, msk, flagp, Qb, Kb, Vb);
    hipLaunchKernelGGL(msum_k, dim3(4), dim3(256), 0, stream, msk, flagp, msumws);
    hipLaunchKernelGGL(kv_k, dim3(48, 16), dim3(256), 0, stream,
                       Kb, Vb, kvws, ksumws, vsumws);
    hipLaunchKernelGGL(out_k, dim3(48, 32), dim3(256), 0, stream,
                       Qb, kvws, ksumws, vsumws, msumws, (float*)d_out);
}

// Round 6
// 488.667 us; speedup vs baseline: 1.3632x; 1.1954x over previous
//
#include <hip/hip_runtime.h>

// CosineSelfAttention  B=4, S=8192, HID=768, NH=12, HD=64, EPS=1e-5
// Round 6: fully deterministic (no atomics). ksum/vsum from fp32 GEMM
// accumulators (gemm_kv epilogue partials); kv via MFMA partials (grid (48,2));
// output matvec uses hi/lo bf16 split of kv (== fp32 precision).
// K,V staged bf16 in d_out (consumed before gemm_q_out overwrites with fp32).

typedef unsigned short u16;
typedef unsigned int u32;

#define B_ 4
#define S_ 8192
#define HID_ 768
#define NH_ 12
#define HD_ 64
#define EPS_ 1e-5f

typedef __attribute__((ext_vector_type(8))) short bf16x8;
typedef __attribute__((ext_vector_type(4))) float f32x4;

__device__ __forceinline__ float bf2f(unsigned int u) {
    u <<= 16;
    return __builtin_bit_cast(float, u);
}
__device__ __forceinline__ u16 f2bf(float f) {
    u32 u = __builtin_bit_cast(u32, f);
    u = u + 0x7fffu + ((u >> 16) & 1u);   // round-to-nearest-even
    return (u16)(u >> 16);
}

#define ASYNC16(gptr, lptr)                                                        \
    __builtin_amdgcn_global_load_lds(                                              \
        (const __attribute__((address_space(1))) void*)(gptr),                     \
        (__attribute__((address_space(3))) void*)(lptr), 16, 0, 0)

// ---------------------------------------------------------------------------
// Kernel 0: dtype sniff (1 = fp32, 0 = bf16)
// ---------------------------------------------------------------------------
__global__ void sniff_k(const void* __restrict__ X, u32* __restrict__ flag)
{
    __shared__ int bad;
    if (threadIdx.x == 0) bad = 0;
    __syncthreads();
    const u16* p = (const u16*)X;
    int loc = 0;
    for (int i = threadIdx.x; i < 8192; i += 256) {
        const u32 u = p[2 * i];
        const u32 e = (u >> 7) & 0xFFu;
        if (e >= 0xF8u) loc = 1;
    }
    if (loc) bad = 1;
    __syncthreads();
    if (threadIdx.x == 0) *flag = (u32)bad;
}

// ---------------------------------------------------------------------------
// Kernel 0b: convert X | Wq,Wk,Wv | mask | biases -> bf16 buffers.
// ---------------------------------------------------------------------------
__global__ __launch_bounds__(256) void conv_k(
    const void* __restrict__ X,
    const void* __restrict__ Wq, const void* __restrict__ Wk, const void* __restrict__ Wv,
    const void* __restrict__ bq, const void* __restrict__ bk, const void* __restrict__ bv,
    const void* __restrict__ mask,
    const u32* __restrict__ flagp,
    u16* __restrict__ Xb, u16* __restrict__ Wb, u16* __restrict__ Mb, u16* __restrict__ Bb)
{
    const int id = blockIdx.x;
    const void* src;
    u16* dst;
    int e;
    if (id < 12288) {                       // X
        src = X; dst = Xb; e = id * 2048 + threadIdx.x * 8;
    } else if (id < 13152) {                // W: 3 x 589824
        const int i = id - 12288;
        const int mat = i / 288;
        e = (i % 288) * 2048 + threadIdx.x * 8;
        src = (mat == 0) ? Wq : (mat == 1) ? Wk : Wv;
        dst = Wb + (size_t)mat * 589824;
    } else if (id < 13168) {                // mask: 32768
        const int i = id - 13152;
        src = mask; dst = Mb; e = i * 2048 + threadIdx.x * 8;
    } else {                                // biases: 3 x 768
        const int i = id - 13168;
        const int e0 = i * 2048 + threadIdx.x * 8;
        if (e0 >= 2304) return;
        const int mat = e0 / 768;
        src = (mat == 0) ? bq : (mat == 1) ? bk : bv;
        dst = Bb + mat * 768;
        e = e0 - mat * 768;
    }
    if (*flagp) {
        const float* s = (const float*)src + e;
        const float4 lo = *(const float4*)(s);
        const float4 hi = *(const float4*)(s + 4);
        uint4 o;
        o.x = (u32)f2bf(lo.x) | ((u32)f2bf(lo.y) << 16);
        o.y = (u32)f2bf(lo.z) | ((u32)f2bf(lo.w) << 16);
        o.z = (u32)f2bf(hi.x) | ((u32)f2bf(hi.y) << 16);
        o.w = (u32)f2bf(hi.z) | ((u32)f2bf(hi.w) << 16);
        *(uint4*)(dst + e) = o;
    } else {
        *(uint4*)(dst + e) = *(const uint4*)((const u16*)src + e);
    }
}

// ---------------------------------------------------------------------------
// Kernel 1: K,V GEMM (+bias; K: mask+cosine norm). 128x128 tile, BK=64.
// Epilogue also emits fp32 column-sum partials: kspart (sum of k-hat rows,
// masked) and vspart (sum of v rows) per row-tile -- deterministic, from
// UNROUNDED accumulators (closer to fp32 reference than summing bf16 K/V).
// ---------------------------------------------------------------------------
__global__ __launch_bounds__(256) void gemm_kv_k(
    const u16* __restrict__ Xb, const u16* __restrict__ Wb,
    const u16* __restrict__ Bb, const u16* __restrict__ Mb,
    u16* __restrict__ Kb, u16* __restrict__ Vb,
    float* __restrict__ kspart, float* __restrict__ vspart)
{
    __shared__ u16 smem[128 * 136];
    __shared__ float colsum[2][128];
    u16* lA = smem;
    u16* lB = smem + 128 * 64;

    const int tid  = threadIdx.x;
    const int lane = tid & 63;
    const int wid  = tid >> 6;
    const int wm   = wid >> 1, wn = wid & 1;

    const int bid   = blockIdx.x;
    const int row_t = bid / 12;
    const int nc    = bid % 12;
    const int mat2  = nc / 6;                 // 0 = K, 1 = V
    const int ncol  = nc % 6;
    const u16* W    = Wb + (size_t)(1 + mat2) * 589824;
    const u16* bias = Bb + (1 + mat2) * 768;
    u16* outb       = (mat2 == 0) ? Kb : Vb;

    const int arow0 = row_t * 128;
    const int brow0 = ncol * 128;

    const int srow = lane >> 3;
    const int sseg = lane & 7;

    f32x4 acc[4][4];
#pragma unroll
    for (int i = 0; i < 4; ++i)
#pragma unroll
        for (int j = 0; j < 4; ++j) acc[i][j] = (f32x4){0.f, 0.f, 0.f, 0.f};

    for (int k0 = 0; k0 < HID_; k0 += 64) {
#pragma unroll
        for (int t = 0; t < 4; ++t) {
            const int chunk = wid * 4 + t;
            const int row = chunk * 8 + srow;
            const int gseg = sseg ^ (row & 7);
            ASYNC16(Xb + (size_t)(arow0 + row) * HID_ + k0 + gseg * 8, lA + chunk * 512);
            ASYNC16(W  + (size_t)(brow0 + row) * HID_ + k0 + gseg * 8, lB + chunk * 512);
        }
        __syncthreads();
#pragma unroll
        for (int ks = 0; ks < 2; ++ks) {
            const int phys = ((ks * 4 + (lane >> 4)) ^ (lane & 7)) * 8;
            bf16x8 af[4], bfr[4];
#pragma unroll
            for (int i = 0; i < 4; ++i)
                af[i] = *(const bf16x8*)(lA + (wm * 64 + i * 16 + (lane & 15)) * 64 + phys);
#pragma unroll
            for (int j = 0; j < 4; ++j)
                bfr[j] = *(const bf16x8*)(lB + (wn * 64 + j * 16 + (lane & 15)) * 64 + phys);
#pragma unroll
            for (int i = 0; i < 4; ++i)
#pragma unroll
                for (int j = 0; j < 4; ++j)
                    acc[i][j] = __builtin_amdgcn_mfma_f32_16x16x32_bf16(af[i], bfr[j], acc[i][j], 0, 0, 0);
        }
        __syncthreads();
    }

    // ---- epilogue: bias; K: mask + cosine norm
    float bias4[4];
#pragma unroll
    for (int j = 0; j < 4; ++j)
        bias4[j] = bf2f(bias[brow0 + wn * 64 + j * 16 + (lane & 15)]);
#pragma unroll
    for (int i = 0; i < 4; ++i)
#pragma unroll
        for (int j = 0; j < 4; ++j)
#pragma unroll
            for (int r = 0; r < 4; ++r) acc[i][j][r] += bias4[j];

    float scale[4][4];
    if (mat2 == 0) {
#pragma unroll
        for (int i = 0; i < 4; ++i) {
#pragma unroll
            for (int r = 0; r < 4; ++r) {
                float ss = 0.f;
#pragma unroll
                for (int j = 0; j < 4; ++j) ss += acc[i][j][r] * acc[i][j][r];
#pragma unroll
                for (int off = 1; off < 16; off <<= 1) ss += __shfl_xor(ss, off, 64);
                const int grow = arow0 + wm * 64 + i * 16 + (lane >> 4) * 4 + r;
                const float mk = bf2f(Mb[grow]);
                const float mf = (mk == 0.f) ? 1.f : 0.f;
                scale[i][r] = mf / (sqrtf(ss) + EPS_);
            }
        }
    } else {
#pragma unroll
        for (int i = 0; i < 4; ++i)
#pragma unroll
            for (int r = 0; r < 4; ++r) scale[i][r] = 1.f;
    }

    // ---- fp32 column-sum partials (rows of this wave -> shfl -> colsum)
    {
        float cs[4];
#pragma unroll
        for (int j = 0; j < 4; ++j) {
            float s = 0.f;
#pragma unroll
            for (int i = 0; i < 4; ++i)
#pragma unroll
                for (int r = 0; r < 4; ++r) s += acc[i][j][r] * scale[i][r];
            s += __shfl_xor(s, 16, 64);
            s += __shfl_xor(s, 32, 64);
            cs[j] = s;
        }
        if (lane < 16) {
#pragma unroll
            for (int j = 0; j < 4; ++j)
                colsum[wm][wn * 64 + j * 16 + lane] = cs[j];
        }
    }

    __syncthreads();   // staging reads + colsum writes done
    if (tid < 128) {
        const float s = colsum[0][tid] + colsum[1][tid];
        float* part = (mat2 == 0) ? kspart : vspart;
        part[row_t * 768 + brow0 + tid] = s;
    }

    // ---- repack + store bf16 K/V
#pragma unroll
    for (int i = 0; i < 4; ++i)
#pragma unroll
        for (int j = 0; j < 4; ++j)
#pragma unroll
            for (int r = 0; r < 4; ++r) {
                const int rr = wm * 64 + i * 16 + (lane >> 4) * 4 + r;
                const int cc = wn * 64 + j * 16 + (lane & 15);
                smem[rr * 136 + cc] = f2bf(acc[i][j][r] * scale[i][r]);
            }
    __syncthreads();
#pragma unroll
    for (int it = 0; it < 8; ++it) {
        const int lin = it * 2048 + tid * 8;
        const int r = lin >> 7;
        const int c = lin & 127;
        const uint4 v = *(const uint4*)(smem + r * 136 + c);
        *(uint4*)(outb + (size_t)(arow0 + r) * HID_ + brow0 + c) = v;
    }
}

// ---------------------------------------------------------------------------
// Kernel 2: msum[b] = count of mask[b,s]==0
// ---------------------------------------------------------------------------
__global__ __launch_bounds__(256) void msum_k(const u16* __restrict__ Mb,
                                              float* __restrict__ msumws)
{
    const int b = blockIdx.x, tid = threadIdx.x;
    float loc = 0.f;
    for (int i = 0; i < 32; ++i) {
        const float mv = bf2f(Mb[b * S_ + i * 256 + tid]);
        loc += (mv == 0.f) ? 1.f : 0.f;
    }
#pragma unroll
    for (int off = 32; off > 0; off >>= 1) loc += __shfl_down(loc, off, 64);
    __shared__ float red[4];
    if ((tid & 63) == 0) red[tid >> 6] = loc;
    __syncthreads();
    if (tid == 0) msumws[b] = red[0] + red[1] + red[2] + red[3];
}

// ---------------------------------------------------------------------------
// Kernel 3: MFMA kv partials (deterministic, no atomics).
// kvpart[by][bh][e*64+d] = sum over 4096 tokens of khat_d * v_e.
// grid (48, 2). LDS transposed tiles lKT[d][s], lVT[e][s], s-seg XOR-swizzled.
// ---------------------------------------------------------------------------
__global__ __launch_bounds__(256) void kvacc_k(
    const u16* __restrict__ Kb, const u16* __restrict__ Vb,
    float* __restrict__ kvpart)
{
    __shared__ u16 lKT[64 * 64];
    __shared__ u16 lVT[64 * 64];
    const int tid = threadIdx.x;
    const int lane = tid & 63;
    const int w = tid >> 6;
    const int bh = blockIdx.x;
    const int b = bh / NH_, h = bh % NH_;
    const int s0 = blockIdx.y * 4096;

    f32x4 akv[4];
#pragma unroll
    for (int j = 0; j < 4; ++j) akv[j] = (f32x4){0.f, 0.f, 0.f, 0.f};

    for (int t = 0; t < 64; ++t) {
        const size_t rbase = (size_t)(b * S_ + s0 + t * 64 + lane) * HID_ + h * 64;
#pragma unroll
        for (int it = 0; it < 2; ++it) {
            const int d0 = 8 * (it * 4 + w);
            union { uint4 q; u16 s[8]; } uk, uv;
            uk.q = *(const uint4*)(Kb + rbase + d0);
            uv.q = *(const uint4*)(Vb + rbase + d0);
            const int s = lane;
#pragma unroll
            for (int m = 0; m < 8; ++m) {
                const int d = d0 + m;
                const int adr = d * 64 + (((s >> 3) ^ (d & 7)) << 3) + (s & 7);
                lKT[adr] = uk.s[m];
                lVT[adr] = uv.s[m];
            }
        }
        __syncthreads();
#pragma unroll
        for (int ks = 0; ks < 2; ++ks) {
            const int phys = ((ks * 4 + (lane >> 4)) ^ (lane & 7)) * 8;
            const bf16x8 ak = *(const bf16x8*)(lKT + (16 * w + (lane & 15)) * 64 + phys);
#pragma unroll
            for (int j = 0; j < 4; ++j) {
                const bf16x8 bv = *(const bf16x8*)(lVT + (j * 16 + (lane & 15)) * 64 + phys);
                akv[j] = __builtin_amdgcn_mfma_f32_16x16x32_bf16(ak, bv, akv[j], 0, 0, 0);
            }
        }
        __syncthreads();
    }

    float* dst = kvpart + ((size_t)blockIdx.y * 48 + bh) * 4096;
    const int drow = 16 * w + (lane >> 4) * 4;
#pragma unroll
    for (int j = 0; j < 4; ++j) {
        const int e = j * 16 + (lane & 15);
#pragma unroll
        for (int r = 0; r < 4; ++r)
            dst[e * 64 + drow + r] = akv[j][r];
    }
}

// ---------------------------------------------------------------------------
// Kernel 4: Q GEMM + fused MFMA matvec epilogue -> fp32 out.
// Preload: deterministic partial sums -> kv hi/lo bf16 split (== fp32),
// ksum/vsum fp32 from gemm_kv partials. grid 1536: row_t(256) x ncol(6).
// ---------------------------------------------------------------------------
__global__ __launch_bounds__(256) void gemm_q_out_k(
    const u16* __restrict__ Xb, const u16* __restrict__ Wb,
    const u16* __restrict__ Bb, const u16* __restrict__ Mb,
    const float* __restrict__ kvpart, const float* __restrict__ kspart,
    const float* __restrict__ vspart, const float* __restrict__ msumws,
    float* __restrict__ out)
{
    __shared__ u16 smem[128 * 64 * 2];      // staging A|B, then qn[128x128 swiz]
    __shared__ u16 ekvH[2 * 64 * 64];       // kv hi bf16: [hd][e][d swiz]
    __shared__ u16 ekvL[2 * 64 * 64];       // kv lo bf16
    __shared__ float ksl[2 * 64];
    __shared__ float vsl[2 * 64];
    __shared__ float dnl[2 * 128];
    u16* lA = smem;
    u16* lB = smem + 128 * 64;

    const int tid  = threadIdx.x;
    const int lane = tid & 63;
    const int wid  = tid >> 6;
    const int wm   = wid >> 1, wn = wid & 1;

    const int bid   = blockIdx.x;
    const int row_t = bid / 6;
    const int ncol  = bid % 6;
    const int b     = row_t >> 6;
    const int arow0 = row_t * 128;
    const int brow0 = ncol * 128;
    const int bh0   = b * NH_ + ncol * 2;

    // ---- preload kv (sum 2 partials -> hi/lo bf16), ksum/vsum (sum 64 tiles)
    for (int it = 0; it < 32; ++it) {
        const int idx = it * 256 + tid;          // 8192 = 2 heads x 64e x 64d
        const int hd = idx >> 12;
        const int e  = (idx >> 6) & 63;
        const int d  = idx & 63;
        const size_t base = ((size_t)(bh0 + hd)) * 4096 + e * 64 + d;
        const float v = kvpart[base] + kvpart[(size_t)48 * 4096 + base];
        const u16 hi = f2bf(v);
        const float rem = v - bf2f(hi);
        const int adr = hd * 4096 + e * 64 + (((d >> 3) ^ (e & 7)) << 3) + (d & 7);
        ekvH[adr] = hi;
        ekvL[adr] = f2bf(rem);
    }
    if (tid < 128) {
        const int hd = tid >> 6, c = tid & 63;
        const int col = (ncol * 2 + hd) * 64 + c;
        float ks = 0.f, vs = 0.f;
        const int rb = b * 64;
        for (int rt = 0; rt < 64; ++rt) {
            ks += kspart[(rb + rt) * 768 + col];
            vs += vspart[(rb + rt) * 768 + col];
        }
        ksl[tid] = ks;
        vsl[tid] = vs;
    }

    const int srow = lane >> 3;
    const int sseg = lane & 7;

    f32x4 acc[4][4];
#pragma unroll
    for (int i = 0; i < 4; ++i)
#pragma unroll
        for (int j = 0; j < 4; ++j) acc[i][j] = (f32x4){0.f, 0.f, 0.f, 0.f};

    for (int k0 = 0; k0 < HID_; k0 += 64) {
#pragma unroll
        for (int t = 0; t < 4; ++t) {
            const int chunk = wid * 4 + t;
            const int row = chunk * 8 + srow;
            const int gseg = sseg ^ (row & 7);
            ASYNC16(Xb + (size_t)(arow0 + row) * HID_ + k0 + gseg * 8, lA + chunk * 512);
            ASYNC16(Wb + (size_t)(brow0 + row) * HID_ + k0 + gseg * 8, lB + chunk * 512);
        }
        __syncthreads();
#pragma unroll
        for (int ks = 0; ks < 2; ++ks) {
            const int phys = ((ks * 4 + (lane >> 4)) ^ (lane & 7)) * 8;
            bf16x8 af[4], bfr[4];
#pragma unroll
            for (int i = 0; i < 4; ++i)
                af[i] = *(const bf16x8*)(lA + (wm * 64 + i * 16 + (lane & 15)) * 64 + phys);
#pragma unroll
            for (int j = 0; j < 4; ++j)
                bfr[j] = *(const bf16x8*)(lB + (wn * 64 + j * 16 + (lane & 15)) * 64 + phys);
#pragma unroll
            for (int i = 0; i < 4; ++i)
#pragma unroll
                for (int j = 0; j < 4; ++j)
                    acc[i][j] = __builtin_amdgcn_mfma_f32_16x16x32_bf16(af[i], bfr[j], acc[i][j], 0, 0, 0);
        }
        __syncthreads();
    }

    // ---- bias + mask + cosine norm
    float bias4[4];
#pragma unroll
    for (int j = 0; j < 4; ++j)
        bias4[j] = bf2f(Bb[brow0 + wn * 64 + j * 16 + (lane & 15)]);
#pragma unroll
    for (int i = 0; i < 4; ++i)
#pragma unroll
        for (int j = 0; j < 4; ++j)
#pragma unroll
            for (int r = 0; r < 4; ++r) acc[i][j][r] += bias4[j];

    float scale[4][4];
#pragma unroll
    for (int i = 0; i < 4; ++i) {
#pragma unroll
        for (int r = 0; r < 4; ++r) {
            float ss = 0.f;
#pragma unroll
            for (int j = 0; j < 4; ++j) ss += acc[i][j][r] * acc[i][j][r];
#pragma unroll
            for (int off = 1; off < 16; off <<= 1) ss += __shfl_xor(ss, off, 64);
            const int grow = arow0 + wm * 64 + i * 16 + (lane >> 4) * 4 + r;
            const float mk = bf2f(Mb[grow]);
            const float mf = (mk == 0.f) ? 1.f : 0.f;
            scale[i][r] = mf / (sqrtf(ss) + EPS_);
        }
    }

    // ---- repack qn bf16 into smem (swizzled), stride 128
#pragma unroll
    for (int i = 0; i < 4; ++i)
#pragma unroll
        for (int j = 0; j < 4; ++j)
#pragma unroll
            for (int r = 0; r < 4; ++r) {
                const int rr = wm * 64 + i * 16 + (lane >> 4) * 4 + r;
                const int cc = wn * 64 + j * 16 + (lane & 15);
                smem[rr * 128 + (((cc >> 3) ^ (rr & 7)) << 3) + (cc & 7)] =
                    f2bf(acc[i][j][r] * scale[i][r]);
            }
    __syncthreads();

    // ---- den = eps + msum + qn . ksum
    {
        const int row = tid & 127, hd = tid >> 7;
        float den = EPS_ + msumws[b];
#pragma unroll
        for (int c = 0; c < 8; ++c) {
            const int colbase = hd * 64 + c * 8;
            const int phys = (((colbase >> 3) ^ (row & 7)) << 3);
            const bf16x8 qv = *(const bf16x8*)(smem + row * 128 + phys);
#pragma unroll
            for (int m = 0; m < 8; ++m)
                den += bf2f((u16)qv[m]) * ksl[colbase + m];
        }
        dnl[hd * 128 + row] = 1.f / den;
    }
    __syncthreads();

    // ---- MFMA matvec: o = qn @ (kvH + kvL)  (head = wn)
    f32x4 o4[4][4];
#pragma unroll
    for (int i = 0; i < 4; ++i)
#pragma unroll
        for (int j = 0; j < 4; ++j) o4[i][j] = (f32x4){0.f, 0.f, 0.f, 0.f};
#pragma unroll
    for (int ks = 0; ks < 2; ++ks) {
        bf16x8 aq[4], bkH[4], bkL[4];
#pragma unroll
        for (int i = 0; i < 4; ++i) {
            const int row = wm * 64 + i * 16 + (lane & 15);
            const int colbase = wn * 64 + ks * 32 + (lane >> 4) * 8;
            const int phys = (((colbase >> 3) ^ (row & 7)) << 3);
            aq[i] = *(const bf16x8*)(smem + row * 128 + phys);
        }
#pragma unroll
        for (int j = 0; j < 4; ++j) {
            const int e = j * 16 + (lane & 15);
            const int physd = (((ks * 4 + (lane >> 4)) ^ (e & 7)) << 3);
            bkH[j] = *(const bf16x8*)(ekvH + wn * 4096 + e * 64 + physd);
            bkL[j] = *(const bf16x8*)(ekvL + wn * 4096 + e * 64 + physd);
        }
#pragma unroll
        for (int i = 0; i < 4; ++i)
#pragma unroll
            for (int j = 0; j < 4; ++j) {
                o4[i][j] = __builtin_amdgcn_mfma_f32_16x16x32_bf16(aq[i], bkH[j], o4[i][j], 0, 0, 0);
                o4[i][j] = __builtin_amdgcn_mfma_f32_16x16x32_bf16(aq[i], bkL[j], o4[i][j], 0, 0, 0);
            }
    }

    // ---- + vsum, x 1/den, store fp32
#pragma unroll
    for (int i = 0; i < 4; ++i) {
#pragma unroll
        for (int r = 0; r < 4; ++r) {
            const int row = wm * 64 + i * 16 + (lane >> 4) * 4 + r;
            const float inv = dnl[wn * 128 + row];
            float* op = out + (size_t)(arow0 + row) * HID_ + brow0 + wn * 64;
#pragma unroll
            for (int j = 0; j < 4; ++j) {
                const int e = j * 16 + (lane & 15);
                op[e] = (o4[i][j][r] + vsl[wn * 64 + e]) * inv;
            }
        }
    }
}

// ---------------------------------------------------------------------------
extern "C" void kernel_launch(void* const* d_in, const int* in_sizes, int n_in,
                              void* d_out, int out_size, void* d_ws, size_t ws_size,
                              hipStream_t stream) {
    const void* X   = d_in[0];
    const void* msk = d_in[1];
    const void* Wq  = d_in[2];
    const void* bq  = d_in[3];
    const void* Wk  = d_in[4];
    const void* bk  = d_in[5];
    const void* Wv  = d_in[6];
    const void* bv  = d_in[7];

    char* ws = (char*)d_ws;
    float* kvpart = (float*)ws;                         // 2*48*4096 = 1.5 MB
    float* kspart = kvpart + 2 * 48 * 4096;             // 256*768   = 0.75 MB
    float* vspart = kspart + 256 * 768;                 // 0.75 MB
    float* msumws = vspart + 256 * 768;                 // 4
    u32*   flagp  = (u32*)(msumws + 4);
    u16* Xb = (u16*)(ws + (4 << 20));                   // 48 MB
    u16* Wb = Xb + (size_t)25165824;                    // 3.375 MB
    u16* Mb = Wb + (size_t)1769472;                     // 64 KB
    u16* Bb = Mb + (size_t)32768;                       // small
    u16* Kb = (u16*)d_out;                              // 48 MB bf16 in d_out
    u16* Vb = Kb + (size_t)32768 * 768;                 // 48 MB bf16 in d_out

    hipLaunchKernelGGL(sniff_k, dim3(1), dim3(256), 0, stream, X, flagp);
    hipLaunchKernelGGL(conv_k, dim3(13170), dim3(256), 0, stream,
                       X, Wq, Wk, Wv, bq, bk, bv, msk, flagp, Xb, Wb, Mb, Bb);
    hipLaunchKernelGGL(gemm_kv_k, dim3(3072), dim3(256), 0, stream,
                       Xb, Wb, Bb, Mb, Kb, Vb, kspart, vspart);
    hipLaunchKernelGGL(msum_k, dim3(4), dim3(256), 0, stream, Mb, msumws);
    hipLaunchKernelGGL(kvacc_k, dim3(48, 2), dim3(256), 0, stream, Kb, Vb, kvpart);
    hipLaunchKernelGGL(gemm_q_out_k, dim3(1536), dim3(256), 0, stream,
                       Xb, Wb, Bb, Mb, kvpart, kspart, vspart, msumws, (float*)d_out);
}